// Round 18
// baseline (171.999 us; speedup 1.0000x reference)
//
#include <hip/hip_runtime.h>

// TripletAngularMarginLoss: bs=16384, d=64 (== number of classes)
// out = mean(relu(0.5 + ap - an)) + mean(relu(0.8-ap)) + mean(relu(an-0.4)) + CE
// ap[i] = min_{t[j]==t[i]} cos(x_i,x_j), an[i] = max_{t[j]!=t[i]} cos(x_i,x_j)
//
// R17 (WIN, 139us): class-encoding augmentation. K=128: A-rows append
// +16*e_cls, B-rows append -16*e_cls => MFMA computes D = cos - 256*[same].
// Mining = pure min/max (2 VALU/elem). ap = mp+256, an = mn.
// R18: fold finalize into mine's last block (saves 1 launch + gap ~10-15us).
// R15's fold regressed via co-compile regalloc perturbation; mitigations:
// __noinline__ finalize body (own frame, called after loop state is dead),
// red/last alias onto Bt (LDS_Block_Size unchanged 32768), mine loop copied
// byte-for-byte from verified R17.

#define N_ROWS 16384
#define KDIM 128

typedef __attribute__((ext_vector_type(8))) short bf16x8;
typedef __attribute__((ext_vector_type(4))) float f32x4;

__device__ inline unsigned short f2bf(float f) {
  unsigned u = __float_as_uint(f);
  unsigned r = u + 0x7fffu + ((u >> 16) & 1u);   // round-to-nearest-even
  return (unsigned short)(r >> 16);
}

// order-preserving float->uint encoding for atomicMin/atomicMax
__device__ inline unsigned enc_key(float f) {
  unsigned u = __float_as_uint(f);
  return (u & 0x80000000u) ? ~u : (u | 0x80000000u);
}
__device__ inline float dec_key(unsigned k) {
  unsigned u = (k & 0x80000000u) ? (k ^ 0x80000000u) : ~k;
  return __uint_as_float(u);
}

// async global->LDS DMA, 16B per lane, dest = lds_base + lane*16 (linear)
__device__ inline void g2lds16(const void* g, void* l) {
  __builtin_amdgcn_global_load_lds(
      (const __attribute__((address_space(1))) void*)g,
      (__attribute__((address_space(3))) void*)l, 16, 0, 0);
}

// ---------------- Kernel A: normalize, augmented bf16 copies, per-row CE -----
// xbA[row] = [bf16(xn), +16*onehot(t)] ; xbB[row] = [bf16(xn), -16*onehot(t)]
// CE: no max-pass (verified R15/R17): |xn|<=1 -> exp in [0.37,2.72], sum<=174.
__global__ void prep_kernel(const float* __restrict__ x, const int* __restrict__ tgt,
                            unsigned short* __restrict__ xbA, unsigned short* __restrict__ xbB,
                            float* __restrict__ ce_row,
                            unsigned* __restrict__ mp_key, unsigned* __restrict__ mn_key) {
  const int row  = blockIdx.x * 4 + (threadIdx.x >> 6);
  const int lane = threadIdx.x & 63;
  float v  = x[row * 64 + lane];
  float ss = v * v;
#pragma unroll
  for (int s = 1; s < 64; s <<= 1) ss += __shfl_xor(ss, s, 64);
  float xn = v * rsqrtf(ss);
  int   t  = tgt[row];                  // wave-uniform
  const unsigned short b = f2bf(xn);
  xbA[row * KDIM + lane] = b;
  xbB[row * KDIM + lane] = b;
  xbA[row * KDIM + 64 + lane] = (lane == t) ? (unsigned short)0x4180u : (unsigned short)0u; // +16
  xbB[row * KDIM + 64 + lane] = (lane == t) ? (unsigned short)0xC180u : (unsigned short)0u; // -16

  float e  = __expf(xn);
  float se = e;
#pragma unroll
  for (int s = 1; s < 64; s <<= 1) se += __shfl_xor(se, s, 64);
  float lse = __logf(se);
  float xt  = __shfl(xn, t, 64);
  if (lane == 0) {
    ce_row[row] = lse - xt;
    mp_key[row] = 0xFFFFFFFFu;          // +inf key for atomicMin
    mn_key[row] = 0u;                   // -inf key for atomicMax
  }
}

// ---- finalize body: __noinline__ so it gets its own regalloc frame and ----
// ---- cannot perturb the mine loop's allocation (R15 lesson, rule #19). ----
__device__ __noinline__ void final_reduce(const unsigned* mp_key, const unsigned* mn_key,
                                          const float* ce_row, float* out, float* red) {
  float s = 0.f;
  for (int i = threadIdx.x; i < N_ROWS; i += 256) {
    unsigned kp = __hip_atomic_load(&mp_key[i], __ATOMIC_RELAXED, __HIP_MEMORY_SCOPE_AGENT);
    unsigned kn = __hip_atomic_load(&mn_key[i], __ATOMIC_RELAXED, __HIP_MEMORY_SCOPE_AGENT);
    float ce = ce_row[i];                    // written by prep (kernel boundary)
    float ap = dec_key(kp) + 256.f;          // undo the -256 class offset
    float an = dec_key(kn);                  // negatives unaffected
    s += fmaxf(0.5f + ap - an, 0.f) + fmaxf(0.8f - ap, 0.f) +
         fmaxf(an - 0.4f, 0.f) + ce;
  }
#pragma unroll
  for (int sh = 1; sh < 64; sh <<= 1) s += __shfl_xor(s, sh, 64);
  const int wv = threadIdx.x >> 6;
  if ((threadIdx.x & 63) == 0) red[wv] = s;
  __syncthreads();
  if (threadIdx.x == 0)
    out[0] = (red[0] + red[1] + red[2] + red[3]) * (1.0f / N_ROWS);
}

// ---------------- Kernel B: augmented MFMA similarity + min/max mining -------
// grid = 128 i-blocks * 16 j-splits = 2048 blocks of 256 threads (4 waves) =
// 4 blocks/CU (launch_bounds(256,4)). Compute loop byte-identical to R17
// (verified 90us). Tail: done-counter elects last block -> final_reduce.
__global__ __launch_bounds__(256, 4)
void mine_kernel(const unsigned short* __restrict__ xbA, const unsigned short* __restrict__ xbB,
                 unsigned* __restrict__ mp_key, unsigned* __restrict__ mn_key,
                 const float* __restrict__ ce_row, const unsigned* __restrict__ pz,
                 unsigned* __restrict__ done, float* __restrict__ out) {
  __shared__ unsigned short Bt[2][4][2048];   // 2 bufs x 4 tiles x 4KB, swizzled

  const int lane    = threadIdx.x & 63;
  const int wv      = threadIdx.x >> 6;
  const int iblk    = blockIdx.x >> 4;
  const int jspl    = blockIdx.x & 15;
  const int rowbase = iblk * 128 + wv * 32;
  const int m = lane & 15, q = lane >> 4;
  const int jbase = jspl * (N_ROWS / 16);

  // A fragments (augmented): lane holds row (rowbase+tr*16+m), K-slice ks:
  // dims ks*32 + q*8 .. +7
  bf16x8 a[2][4];
#pragma unroll
  for (int tr = 0; tr < 2; ++tr) {
    const unsigned short* p = xbA + (rowbase + tr * 16 + m) * KDIM + q * 8;
#pragma unroll
    for (int ks = 0; ks < 4; ++ks) a[tr][ks] = *(const bf16x8*)(p + ks * 32);
  }

  float mp[8], mn[8];
#pragma unroll
  for (int k = 0; k < 8; ++k) { mp[k] = __builtin_inff(); mn[k] = -__builtin_inff(); }

  // staging: thread covers col ct of each tile, granule gsel = (lane&15)^ct
  const int ct   = wv * 4 + (lane >> 4);
  const int gsel = (lane & 15) ^ ct;
  const unsigned short* srcb = xbB + (jbase + ct) * KDIM + gsel * 8;

#define STAGE(P_, BUF)                                                            \
  do {                                                                            \
    _Pragma("unroll")                                                             \
    for (int ti = 0; ti < 4; ++ti)                                                \
      g2lds16(srcb + ((P_) * 64 + ti * 16) * KDIM,                                \
              (unsigned short*)&Bt[(BUF)][ti][0] + wv * 512 + lane * 8);          \
  } while (0)

  STAGE(0, 0);
  __syncthreads();

  // swizzled fragment-read byte offsets (constant per lane), one per K-slice
  int roff[4];
#pragma unroll
  for (int ks = 0; ks < 4; ++ks)
    roff[ks] = m * 256 + ((ks * 64 + q * 16) ^ (m << 4));

  for (int ph = 0; ph < 16; ++ph) {
    const int pb = ph & 1;
    if (ph < 15) STAGE(ph + 1, pb ^ 1);
#pragma unroll 1
    for (int j4 = 0; j4 < 4; ++j4) {
      const char* tb = (const char*)&Bt[pb][j4][0];
      const bf16x8 cb0 = *(const bf16x8*)(tb + roff[0]);
      const bf16x8 cb1 = *(const bf16x8*)(tb + roff[1]);
      const bf16x8 cb2 = *(const bf16x8*)(tb + roff[2]);
      const bf16x8 cb3 = *(const bf16x8*)(tb + roff[3]);

#pragma unroll
      for (int tr = 0; tr < 2; ++tr) {
        f32x4 acc = {0.f, 0.f, 0.f, 0.f};
        acc = __builtin_amdgcn_mfma_f32_16x16x32_bf16(a[tr][0], cb0, acc, 0, 0, 0);
        acc = __builtin_amdgcn_mfma_f32_16x16x32_bf16(a[tr][1], cb1, acc, 0, 0, 0);
        acc = __builtin_amdgcn_mfma_f32_16x16x32_bf16(a[tr][2], cb2, acc, 0, 0, 0);
        acc = __builtin_amdgcn_mfma_f32_16x16x32_bf16(a[tr][3], cb3, acc, 0, 0, 0);
        // D = cos - 256*pos: mining is pure min/max (2 VALU per element)
#pragma unroll
        for (int r = 0; r < 4; ++r) {
          const int k = tr * 4 + r;
          mp[k] = fminf(mp[k], acc[r]);
          mn[k] = fmaxf(mn[k], acc[r]);
        }
      }
    }
    __syncthreads();   // one vmcnt-drain + barrier per 4-tile phase
  }
#undef STAGE

  // reduce across the 16 lanes (m = 0..15) inside each q-group
#pragma unroll
  for (int s = 1; s < 16; s <<= 1) {
#pragma unroll
    for (int k = 0; k < 8; ++k) {
      mp[k] = fminf(mp[k], __shfl_xor(mp[k], s, 64));
      mn[k] = fmaxf(mn[k], __shfl_xor(mn[k], s, 64));
    }
  }
  if (m == 0) {
#pragma unroll
    for (int tr = 0; tr < 2; ++tr)
#pragma unroll
      for (int r = 0; r < 4; ++r) {
        const int row = rowbase + tr * 16 + q * 4 + r;
        atomicMin(&mp_key[row], enc_key(mp[tr * 4 + r]));
        atomicMax(&mn_key[row], enc_key(mn[tr * 4 + r]));
      }
  }

  // ---- last-block finalize (done-counter; R11/R12-verified pattern) ----
  float*    red   = (float*)&Bt[0][0][0];       // alias dead LDS (no size growth)
  unsigned* lastw = (unsigned*)&Bt[1][0][0];
  __syncthreads();                     // drains this block's atomics (vmcnt)
  if (threadIdx.x == 0) {
    __threadfence();
    unsigned old = atomicAdd(done, 1u);
    lastw[0] = (old == pz[0] + (unsigned)gridDim.x - 1u) ? 1u : 0u;
  }
  __syncthreads();
  if (lastw[0] == 0u) return;
  __threadfence();                     // acquire side before reading all keys
  final_reduce(mp_key, mn_key, ce_row, out, red);
}

extern "C" void kernel_launch(void* const* d_in, const int* in_sizes, int n_in,
                              void* d_out, int out_size, void* d_ws, size_t ws_size,
                              hipStream_t stream) {
  const float* x   = (const float*)d_in[0];
  const int*   tgt = (const int*)d_in[1];
  char* ws = (char*)d_ws;

  unsigned short* xbA    = (unsigned short*)ws;                          // 4 MB augmented (A)
  unsigned short* xbB    = (unsigned short*)(ws + (4u << 20));           // 4 MB augmented (B)
  unsigned*       mp_key = (unsigned*)(ws + (8u << 20));                 // 64 KB
  unsigned*       mn_key = (unsigned*)(ws + (8u << 20) + (64u << 10));   // 64 KB
  float*          ce_row = (float*)(ws + (8u << 20) + (128u << 10));     // 64 KB
  unsigned*       done   = (unsigned*)(ws + (8u << 20) + (192u << 10));  // 4 B (poison base)
  unsigned*       pz     = done + 1;                                     // reserved, never written
  float*          out    = (float*)d_out;

  prep_kernel<<<N_ROWS / 4, 256, 0, stream>>>(x, tgt, xbA, xbB, ce_row, mp_key, mn_key);
  mine_kernel<<<(N_ROWS / 128) * 16, 256, 0, stream>>>(xbA, xbB, mp_key, mn_key,
                                                       ce_row, pz, done, out);
}

// Round 19
// 142.717 us; speedup vs baseline: 1.2052x; 1.2052x over previous
//
#include <hip/hip_runtime.h>

// TripletAngularMarginLoss: bs=16384, d=64 (== number of classes)
// out = mean(relu(0.5 + ap - an)) + mean(relu(0.8-ap)) + mean(relu(an-0.4)) + CE
// ap[i] = min_{t[j]==t[i]} cos(x_i,x_j), an[i] = max_{t[j]!=t[i]} cos(x_i,x_j)
//
// R17 (WIN, 139us): class-encoding augmentation. K=128: rows carry a class
// block so MFMA computes D = cos - 256*[same class]; mining = pure min/max.
// R18 (fold attempt #2) regressed 90->123us with identical VGPR/LDS/WRITE:
// co-compiled tail perturbs SCHEDULING even when allocation is protected.
// 3-launch structure is mandatory (twice-measured).
// R19 = R17 + one micro-opt: xbA eliminated. Single augmented buffer xb
// holds [bf16(xn), -16*onehot(t)]; mine derives A-frags by sign-flipping the
// class half in-register (XOR 0x8000 per bf16; (+16 e_t).(-16 e_t) = -256d,
// -0 entries contribute 0). prep writes 4MB not 8; mine FETCH drops ~4MB.

#define N_ROWS 16384
#define KDIM 128

typedef __attribute__((ext_vector_type(8))) short bf16x8;
typedef __attribute__((ext_vector_type(4))) float f32x4;
typedef __attribute__((ext_vector_type(4))) unsigned int uint4v;

__device__ inline unsigned short f2bf(float f) {
  unsigned u = __float_as_uint(f);
  unsigned r = u + 0x7fffu + ((u >> 16) & 1u);   // round-to-nearest-even
  return (unsigned short)(r >> 16);
}

// order-preserving float->uint encoding for atomicMin/atomicMax
__device__ inline unsigned enc_key(float f) {
  unsigned u = __float_as_uint(f);
  return (u & 0x80000000u) ? ~u : (u | 0x80000000u);
}
__device__ inline float dec_key(unsigned k) {
  unsigned u = (k & 0x80000000u) ? (k ^ 0x80000000u) : ~k;
  return __uint_as_float(u);
}

// async global->LDS DMA, 16B per lane, dest = lds_base + lane*16 (linear)
__device__ inline void g2lds16(const void* g, void* l) {
  __builtin_amdgcn_global_load_lds(
      (const __attribute__((address_space(1))) void*)g,
      (__attribute__((address_space(3))) void*)l, 16, 0, 0);
}

// negate all 8 bf16 lanes of a fragment (sign-bit XOR; -0 acts as 0 in MFMA)
__device__ inline bf16x8 negbf8(bf16x8 v) {
  uint4v u;
  __builtin_memcpy(&u, &v, 16);
  u ^= (uint4v){0x80008000u, 0x80008000u, 0x80008000u, 0x80008000u};
  bf16x8 r;
  __builtin_memcpy(&r, &u, 16);
  return r;
}

// ---------------- Kernel A: normalize, augmented bf16 copy, per-row CE -------
// xb[row] = [bf16(xn), -16*onehot(t)]  (B-side encoding; A-side derived)
// CE: no max-pass (verified R15/R17): |xn|<=1 -> exp in [0.37,2.72], sum<=174.
__global__ void prep_kernel(const float* __restrict__ x, const int* __restrict__ tgt,
                            unsigned short* __restrict__ xb, float* __restrict__ ce_row,
                            unsigned* __restrict__ mp_key, unsigned* __restrict__ mn_key,
                            float* __restrict__ out) {
  const int row  = blockIdx.x * 4 + (threadIdx.x >> 6);
  const int lane = threadIdx.x & 63;
  float v  = x[row * 64 + lane];
  float ss = v * v;
#pragma unroll
  for (int s = 1; s < 64; s <<= 1) ss += __shfl_xor(ss, s, 64);
  float xn = v * rsqrtf(ss);
  int   t  = tgt[row];                  // wave-uniform
  xb[row * KDIM + lane] = f2bf(xn);
  xb[row * KDIM + 64 + lane] = (lane == t) ? (unsigned short)0xC180u : (unsigned short)0u; // -16

  float e  = __expf(xn);
  float se = e;
#pragma unroll
  for (int s = 1; s < 64; s <<= 1) se += __shfl_xor(se, s, 64);
  float lse = __logf(se);
  float xt  = __shfl(xn, t, 64);
  if (lane == 0) {
    ce_row[row] = lse - xt;
    mp_key[row] = 0xFFFFFFFFu;          // +inf key for atomicMin
    mn_key[row] = 0u;                   // -inf key for atomicMax
  }
  if (blockIdx.x == 0 && threadIdx.x == 0) out[0] = 0.f;
}

// ---------------- Kernel B: augmented MFMA similarity + min/max mining -------
// grid = 128 i-blocks * 16 j-splits = 2048 blocks of 256 threads (4 waves) =
// 4 blocks/CU (launch_bounds(256,4)). R17 loop verbatim; only A-frag init
// changed (load from xb, sign-flip class half ks=2,3).
__global__ __launch_bounds__(256, 4)
void mine_kernel(const unsigned short* __restrict__ xb,
                 unsigned* __restrict__ mp_key, unsigned* __restrict__ mn_key) {
  __shared__ unsigned short Bt[2][4][2048];   // 2 bufs x 4 tiles x 4KB, swizzled

  const int lane    = threadIdx.x & 63;
  const int wv      = threadIdx.x >> 6;
  const int iblk    = blockIdx.x >> 4;
  const int jspl    = blockIdx.x & 15;
  const int rowbase = iblk * 128 + wv * 32;
  const int m = lane & 15, q = lane >> 4;
  const int jbase = jspl * (N_ROWS / 16);

  // A fragments (augmented): lane holds row (rowbase+tr*16+m), K-slice ks:
  // dims ks*32 + q*8 .. +7. Class half (ks 2,3) sign-flipped: -16 -> +16.
  bf16x8 a[2][4];
#pragma unroll
  for (int tr = 0; tr < 2; ++tr) {
    const unsigned short* p = xb + (rowbase + tr * 16 + m) * KDIM + q * 8;
#pragma unroll
    for (int ks = 0; ks < 4; ++ks) {
      bf16x8 f = *(const bf16x8*)(p + ks * 32);
      a[tr][ks] = (ks >= 2) ? negbf8(f) : f;
    }
  }

  float mp[8], mn[8];
#pragma unroll
  for (int k = 0; k < 8; ++k) { mp[k] = __builtin_inff(); mn[k] = -__builtin_inff(); }

  // staging: thread covers col ct of each tile, granule gsel = (lane&15)^ct
  const int ct   = wv * 4 + (lane >> 4);
  const int gsel = (lane & 15) ^ ct;
  const unsigned short* srcb = xb + (jbase + ct) * KDIM + gsel * 8;

#define STAGE(P_, BUF)                                                            \
  do {                                                                            \
    _Pragma("unroll")                                                             \
    for (int ti = 0; ti < 4; ++ti)                                                \
      g2lds16(srcb + ((P_) * 64 + ti * 16) * KDIM,                                \
              (unsigned short*)&Bt[(BUF)][ti][0] + wv * 512 + lane * 8);          \
  } while (0)

  STAGE(0, 0);
  __syncthreads();

  // swizzled fragment-read byte offsets (constant per lane), one per K-slice
  int roff[4];
#pragma unroll
  for (int ks = 0; ks < 4; ++ks)
    roff[ks] = m * 256 + ((ks * 64 + q * 16) ^ (m << 4));

  for (int ph = 0; ph < 16; ++ph) {
    const int pb = ph & 1;
    if (ph < 15) STAGE(ph + 1, pb ^ 1);
#pragma unroll 1
    for (int j4 = 0; j4 < 4; ++j4) {
      const char* tb = (const char*)&Bt[pb][j4][0];
      const bf16x8 cb0 = *(const bf16x8*)(tb + roff[0]);
      const bf16x8 cb1 = *(const bf16x8*)(tb + roff[1]);
      const bf16x8 cb2 = *(const bf16x8*)(tb + roff[2]);
      const bf16x8 cb3 = *(const bf16x8*)(tb + roff[3]);

#pragma unroll
      for (int tr = 0; tr < 2; ++tr) {
        f32x4 acc = {0.f, 0.f, 0.f, 0.f};
        acc = __builtin_amdgcn_mfma_f32_16x16x32_bf16(a[tr][0], cb0, acc, 0, 0, 0);
        acc = __builtin_amdgcn_mfma_f32_16x16x32_bf16(a[tr][1], cb1, acc, 0, 0, 0);
        acc = __builtin_amdgcn_mfma_f32_16x16x32_bf16(a[tr][2], cb2, acc, 0, 0, 0);
        acc = __builtin_amdgcn_mfma_f32_16x16x32_bf16(a[tr][3], cb3, acc, 0, 0, 0);
        // D = cos - 256*pos: mining is pure min/max (2 VALU per element)
#pragma unroll
        for (int r = 0; r < 4; ++r) {
          const int k = tr * 4 + r;
          mp[k] = fminf(mp[k], acc[r]);
          mn[k] = fmaxf(mn[k], acc[r]);
        }
      }
    }
    __syncthreads();   // one vmcnt-drain + barrier per 4-tile phase
  }
#undef STAGE

  // reduce across the 16 lanes (m = 0..15) inside each q-group
#pragma unroll
  for (int s = 1; s < 16; s <<= 1) {
#pragma unroll
    for (int k = 0; k < 8; ++k) {
      mp[k] = fminf(mp[k], __shfl_xor(mp[k], s, 64));
      mn[k] = fmaxf(mn[k], __shfl_xor(mn[k], s, 64));
    }
  }
  if (m == 0) {
#pragma unroll
    for (int tr = 0; tr < 2; ++tr)
#pragma unroll
      for (int r = 0; r < 4; ++r) {
        const int row = rowbase + tr * 16 + q * 4 + r;
        atomicMin(&mp_key[row], enc_key(mp[tr * 4 + r]));
        atomicMax(&mn_key[row], enc_key(mn[tr * 4 + r]));
      }
  }
}

// ---------------- Kernel C: final reduction (8 blocks, float atomicAdd) ------
__global__ void finalize_kernel(const unsigned* __restrict__ mp_key, const unsigned* __restrict__ mn_key,
                                const float* __restrict__ ce_row, float* __restrict__ out) {
  __shared__ float red[16];
  float s = 0.f;
#pragma unroll
  for (int it = 0; it < 2; ++it) {
    const int r = it * 8192 + blockIdx.x * 1024 + threadIdx.x;
    float ap = dec_key(mp_key[r]) + 256.f;   // undo the -256 class offset
    float an = dec_key(mn_key[r]);           // negatives unaffected
    s += fmaxf(0.5f + ap - an, 0.f) + fmaxf(0.8f - ap, 0.f) +
         fmaxf(an - 0.4f, 0.f) + ce_row[r];
  }
#pragma unroll
  for (int sh = 1; sh < 64; sh <<= 1) s += __shfl_xor(s, sh, 64);
  const int wv = threadIdx.x >> 6;
  if ((threadIdx.x & 63) == 0) red[wv] = s;
  __syncthreads();
  if (threadIdx.x == 0) {
    float t = 0.f;
#pragma unroll
    for (int w = 0; w < 16; ++w) t += red[w];
    atomicAdd(out, t * (1.0f / N_ROWS));
  }
}

extern "C" void kernel_launch(void* const* d_in, const int* in_sizes, int n_in,
                              void* d_out, int out_size, void* d_ws, size_t ws_size,
                              hipStream_t stream) {
  const float* x   = (const float*)d_in[0];
  const int*   tgt = (const int*)d_in[1];
  char* ws = (char*)d_ws;

  unsigned short* xb     = (unsigned short*)ws;                          // 4 MB augmented
  unsigned*       mp_key = (unsigned*)(ws + (4u << 20));                 // 64 KB
  unsigned*       mn_key = (unsigned*)(ws + (4u << 20) + (64u << 10));   // 64 KB
  float*          ce_row = (float*)(ws + (4u << 20) + (128u << 10));     // 64 KB
  float*          out    = (float*)d_out;

  prep_kernel<<<N_ROWS / 4, 256, 0, stream>>>(x, tgt, xb, ce_row, mp_key, mn_key, out);
  mine_kernel<<<(N_ROWS / 128) * 16, 256, 0, stream>>>(xb, mp_key, mn_key);
  finalize_kernel<<<8, 1024, 0, stream>>>(mp_key, mn_key, ce_row, out);
}